// Round 4
// baseline (239.423 us; speedup 1.0000x reference)
//
#include <hip/hip_runtime.h>
#include <math.h>

#define HIDDEN   2048
#define NEXPERT  64
#define TOPK     8
#define NTOK     16384
#define TOKB     64          // tokens per block (four 16-row M tiles)
#define RSQRT_H  0.02209708691207961
#define WSCALE   64.0f       // keeps f16 Wl split in normal range; undone in epilogue

typedef __attribute__((ext_vector_type(8))) _Float16       v8h;
typedef __attribute__((ext_vector_type(8))) unsigned short v8u;
typedef __attribute__((ext_vector_type(4))) float          v4f;

static __device__ __forceinline__ unsigned short f16b(float x) {
    return __builtin_bit_cast(unsigned short, (_Float16)x);   // v_cvt_f16_f32 (RNE)
}
static __device__ __forceinline__ float f16f(unsigned short u) {
    return (float)__builtin_bit_cast(_Float16, u);
}

// Weight prep into B-fragment order: wf[ks(64)][nt(4)][hl(2)][lane(64)][j(8)] f16.
// B[k][n]: n = nt*16 + (lane&15), k = ks*32 + (lane>>4)*8 + j.  v = w*scale*64.
// Also zeroes out_c (replaces a separate hipMemsetAsync dispatch).
__global__ __launch_bounds__(256) void prep_wf(
    const float* __restrict__ w, const float* __restrict__ scale,
    unsigned short* __restrict__ wf, float* __restrict__ out_c)
{
    int i    = blockIdx.x * 256 + threadIdx.x;   // 131072
    if (i < NEXPERT) out_c[i] = 0.f;
    int j    = i & 7;
    int lane = (i >> 3) & 63;
    int nt   = (i >> 9) & 3;
    int ks   = i >> 11;
    int e    = nt * 16 + (lane & 15);
    int k    = ks * 32 + (lane >> 4) * 8 + j;
    float v  = w[e * HIDDEN + k] * scale[k] * WSCALE;
    unsigned short vh = f16b(v);
    unsigned short vl = f16b(v - f16f(vh));      // Dekker split: v - hi exact in f32
    size_t base = (((size_t)(ks * 4 + nt) * 2) * 64 + lane) * 8 + j;
    wf[base]       = vh;                          // hl=0
    wf[base + 512] = vl;                          // hl=1 (stride 64*8)
}

// Convert 8 f32 -> split-f16 hi/lo fragments; accumulate sum of squares.
static __device__ __forceinline__ void cvt8(
    float4 a, float4 b, v8h& ah, v8h& al, float& ss)
{
    float vv[8] = {a.x, a.y, a.z, a.w, b.x, b.y, b.z, b.w};
    v8u uh, ul;
#pragma unroll
    for (int j = 0; j < 8; ++j) {
        float v = vv[j];
        unsigned short hh = f16b(v);
        uh[j] = hh;
        ul[j] = f16b(v - f16f(hh));   // exact residual in f32, then RNE
        ss    = fmaf(v, v, ss);
    }
    ah = __builtin_bit_cast(v8h, uh);
    al = __builtin_bit_cast(v8h, ul);
}

// 64 tokens/block, 512 thr (8 waves), grid = 256 = exactly 1 block/CU.
// Wave w owns k-range [w*256, w*256+256) for ALL 64 tokens (four 16-row
// M tiles): wf L2/L3 re-read traffic halves again vs TOKB=32 (128 MB total)
// and each batched B-fragment group feeds 48 MFMAs. A-fragments load
// straight from global with depth-1 register prefetch; all 8 B-fragments
// of a k-step load into named registers behind a sched_barrier(0) fence
// (R3-proven: forces back-to-back issue, late waits).
// logits_raw = Xh*Wh + Xh*Wl + Xl*Wh  (split-f16, per-acc order == R3).
__global__ __launch_bounds__(512, 2) void router_main(
    const float* __restrict__ h, const unsigned short* __restrict__ wf,
    const float* __restrict__ pes,
    float* __restrict__ out_w, float* __restrict__ out_i, float* __restrict__ out_c)
{
    __shared__ __align__(16) float lg[8 * 64 * 66];   // [wave][token][expert+pad] 135168B
    __shared__ float lss[8 * 64];                     // [wave][token] partial sumsq
    __shared__ int   hist[NEXPERT];

    const int tid  = (int)threadIdx.x;
    const int w    = __builtin_amdgcn_readfirstlane(tid >> 6);   // wave 0..7
    const int lane = tid & 63;
    const int m    = lane & 15;                                   // A row idx
    const int quad = lane >> 4;
    const int t0   = (int)blockIdx.x * TOKB;

    if (tid < NEXPERT) hist[tid] = 0;

    // A sources: token rows t*16+m, k = w*256 + s*32 + quad*8 + j
    const float* xp0 = h + (size_t)(t0 + m) * HIDDEN + w * 256 + quad * 8;
    const float* xp1 = xp0 + (size_t)16 * HIDDEN;
    const float* xp2 = xp0 + (size_t)32 * HIDDEN;
    const float* xp3 = xp0 + (size_t)48 * HIDDEN;
    // B source: ks = w*8 + s; frag base = ks*4096 + nt*1024 (+512 for lo)
    const unsigned short* wq = wf + (size_t)(w * 8) * 4096 + (size_t)lane * 8;

    v4f acc[4][4];                                    // [tile][nt]
#pragma unroll
    for (int t = 0; t < 4; ++t)
#pragma unroll
        for (int nt = 0; nt < 4; ++nt) acc[t][nt] = (v4f)0.f;
    float ss[4] = {0.f, 0.f, 0.f, 0.f};

    float4 ca[4], cb[4];
    ca[0] = *(const float4*)xp0; cb[0] = *(const float4*)(xp0 + 4);
    ca[1] = *(const float4*)xp1; cb[1] = *(const float4*)(xp1 + 4);
    ca[2] = *(const float4*)xp2; cb[2] = *(const float4*)(xp2 + 4);
    ca[3] = *(const float4*)xp3; cb[3] = *(const float4*)(xp3 + 4);

#pragma unroll
    for (int s = 0; s < 8; ++s) {
        // ---- issue ALL memory for this step first (8 B-frags + next X), then fence
        const unsigned short* bq = wq + (size_t)s * 4096;
        v8h bh[4], bl[4];
#pragma unroll
        for (int nt = 0; nt < 4; ++nt) {
            bh[nt] = *(const v8h*)(bq + nt * 1024);
            bl[nt] = *(const v8h*)(bq + nt * 1024 + 512);
        }
        float4 na[4], nb[4];
        if (s < 7) {
            na[0] = *(const float4*)(xp0 + (s + 1) * 32);
            nb[0] = *(const float4*)(xp0 + (s + 1) * 32 + 4);
            na[1] = *(const float4*)(xp1 + (s + 1) * 32);
            nb[1] = *(const float4*)(xp1 + (s + 1) * 32 + 4);
            na[2] = *(const float4*)(xp2 + (s + 1) * 32);
            nb[2] = *(const float4*)(xp2 + (s + 1) * 32 + 4);
            na[3] = *(const float4*)(xp3 + (s + 1) * 32);
            nb[3] = *(const float4*)(xp3 + (s + 1) * 32 + 4);
        }
        __builtin_amdgcn_sched_barrier(0);   // loads above, consumers below

        // ---- per tile: convert current X (overlaps load latency), 12 MFMAs.
        // Per-acc order (ah*bh, ah*bl, al*bh) identical to R3.
#pragma unroll
        for (int t = 0; t < 4; ++t) {
            v8h ah, al;
            cvt8(ca[t], cb[t], ah, al, ss[t]);
#pragma unroll
            for (int nt = 0; nt < 4; ++nt) {
                acc[t][nt] = __builtin_amdgcn_mfma_f32_16x16x32_f16(ah, bh[nt], acc[t][nt], 0, 0, 0);
                acc[t][nt] = __builtin_amdgcn_mfma_f32_16x16x32_f16(ah, bl[nt], acc[t][nt], 0, 0, 0);
                acc[t][nt] = __builtin_amdgcn_mfma_f32_16x16x32_f16(al, bh[nt], acc[t][nt], 0, 0, 0);
            }
        }

        if (s < 7) {
#pragma unroll
            for (int t = 0; t < 4; ++t) { ca[t] = na[t]; cb[t] = nb[t]; }
        }
    }

    // ---- sum of squares: lane holds quad's 64-float share of rows t*16+m
#pragma unroll
    for (int t = 0; t < 4; ++t) {
        float s = ss[t];
        s += __shfl_xor(s, 16, 64);
        s += __shfl_xor(s, 32, 64);
        if (lane < 16) lss[w * 64 + t * 16 + lane] = s;
    }

    // ---- raw logit partials: D row=(quad*4+reg)=token-in-tile, col=nt*16+m
#pragma unroll
    for (int t = 0; t < 4; ++t)
#pragma unroll
        for (int nt = 0; nt < 4; ++nt)
#pragma unroll
            for (int r = 0; r < 4; ++r)
                lg[(w * 64 + t * 16 + quad * 4 + r) * 66 + nt * 16 + m] = acc[t][nt][r];
    __syncthreads();

    // ---- top-8 epilogue (R0-verified): wave w handles tokens w*8..w*8+7
    for (int i = 0; i < 8; ++i) {
        const int tok = w * 8 + i;
        float l0 = lg[(0 * 64 + tok) * 66 + lane], l1 = lg[(1 * 64 + tok) * 66 + lane];
        float l2 = lg[(2 * 64 + tok) * 66 + lane], l3 = lg[(3 * 64 + tok) * 66 + lane];
        float l4 = lg[(4 * 64 + tok) * 66 + lane], l5 = lg[(5 * 64 + tok) * 66 + lane];
        float l6 = lg[(6 * 64 + tok) * 66 + lane], l7 = lg[(7 * 64 + tok) * 66 + lane];
        float lsum = ((l0 + l1) + (l2 + l3)) + ((l4 + l5) + (l6 + l7));
        float q01 = lss[0 * 64 + tok] + lss[1 * 64 + tok];
        float q23 = lss[2 * 64 + tok] + lss[3 * 64 + tok];
        float q45 = lss[4 * 64 + tok] + lss[5 * 64 + tok];
        float q67 = lss[6 * 64 + tok] + lss[7 * 64 + tok];
        double sst = (double)((q01 + q23) + (q45 + q67));
        double rr  = 1.0 / sqrt(sst * (1.0 / (double)HIDDEN) + 1e-6);
        float logit = (float)((double)lsum * rr * (RSQRT_H / (double)WSCALE));

        float work = logit;
        float myval = 0.f; int myidx = 0; float m0 = 0.f;
#pragma unroll
        for (int j = 0; j < TOPK; ++j) {
            float mx = work;
#pragma unroll
            for (int off = 32; off; off >>= 1) mx = fmaxf(mx, __shfl_xor(mx, off, 64));
            unsigned long long msk = __ballot(work == mx);
            int src = __ffsll((long long)msk) - 1;   // ties -> lowest index (jax)
            if (j == 0) m0 = mx;
            if (lane == j) { myval = mx; myidx = src; }
            if (lane == src) work = -3.402823466e38f;
        }

        float ev = (lane < TOPK) ? expf(myval - m0) : 0.f;
        float es = ev;
        es += __shfl_xor(es, 1, 64);
        es += __shfl_xor(es, 2, 64);
        es += __shfl_xor(es, 4, 64);
        if (lane < TOPK) {
            float wgt = (ev / es) * pes[myidx];
            size_t o = (size_t)(t0 + tok) * TOPK + lane;
            out_w[o] = wgt;
            out_i[o] = (float)myidx;                 // d_out read as float32
            atomicAdd(&hist[myidx], 1);
        }
    }

    __syncthreads();
    if (tid < NEXPERT)
        atomicAdd(&out_c[tid], (float)hist[tid]);    // counts are exact small ints
}

extern "C" void kernel_launch(void* const* d_in, const int* in_sizes, int n_in,
                              void* d_out, int out_size, void* d_ws, size_t ws_size,
                              hipStream_t stream) {
    const float* h     = (const float*)d_in[0];   // [4,4096,2048] f32
    const float* scale = (const float*)d_in[1];   // [2048] f32
    const float* w     = (const float*)d_in[2];   // [64,2048] f32
    const float* pes   = (const float*)d_in[3];   // [64] f32

    unsigned short* wf = (unsigned short*)d_ws;   // 512 KB f16 fragment bank

    float* out_w = (float*)d_out;                                  // [16384,8]
    float* out_i = (float*)d_out + (size_t)NTOK * TOPK;            // [16384,8] idx-as-f32
    float* out_c = (float*)d_out + (size_t)NTOK * TOPK * 2;        // [64]

    prep_wf<<<512, 256, 0, stream>>>(w, scale, wf, out_c);

    // 256 blocks x 512 thr (8 waves); exactly 1 block/CU
    router_main<<<NTOK / TOKB, 512, 0, stream>>>(h, wf, pes, out_w, out_i, out_c);
}

// Round 5
// 239.276 us; speedup vs baseline: 1.0006x; 1.0006x over previous
//
#include <hip/hip_runtime.h>
#include <math.h>

#define HIDDEN   2048
#define NEXPERT  64
#define TOPK     8
#define NTOK     16384
#define TOKB     64          // tokens per block (four 16-row M tiles)
#define RSQRT_H  0.02209708691207961
#define WSCALE   64.0f       // keeps f16 Wl split in normal range; undone in epilogue

typedef __attribute__((ext_vector_type(8))) _Float16       v8h;
typedef __attribute__((ext_vector_type(8))) unsigned short v8u;
typedef __attribute__((ext_vector_type(4))) float          v4f;

static __device__ __forceinline__ unsigned short f16b(float x) {
    return __builtin_bit_cast(unsigned short, (_Float16)x);   // v_cvt_f16_f32 (RNE)
}
static __device__ __forceinline__ float f16f(unsigned short u) {
    return (float)__builtin_bit_cast(_Float16, u);
}

// Weight prep into B-fragment order: wf[ks(64)][nt(4)][hl(2)][lane(64)][j(8)] f16.
// B[k][n]: n = nt*16 + (lane&15), k = ks*32 + (lane>>4)*8 + j.  v = w*scale*64.
// Also zeroes out_c (replaces a separate hipMemsetAsync dispatch).
__global__ __launch_bounds__(256) void prep_wf(
    const float* __restrict__ w, const float* __restrict__ scale,
    unsigned short* __restrict__ wf, float* __restrict__ out_c)
{
    int i    = blockIdx.x * 256 + threadIdx.x;   // 131072
    if (i < NEXPERT) out_c[i] = 0.f;
    int j    = i & 7;
    int lane = (i >> 3) & 63;
    int nt   = (i >> 9) & 3;
    int ks   = i >> 11;
    int e    = nt * 16 + (lane & 15);
    int k    = ks * 32 + (lane >> 4) * 8 + j;
    float v  = w[e * HIDDEN + k] * scale[k] * WSCALE;
    unsigned short vh = f16b(v);
    unsigned short vl = f16b(v - f16f(vh));      // Dekker split: v - hi exact in f32
    size_t base = (((size_t)(ks * 4 + nt) * 2) * 64 + lane) * 8 + j;
    wf[base]       = vh;                          // hl=0
    wf[base + 512] = vl;                          // hl=1 (stride 64*8)
}

// Convert 8 f32 -> split-f16 hi/lo fragments; accumulate sum of squares.
static __device__ __forceinline__ void cvt8(
    float4 a, float4 b, v8h& ah, v8h& al, float& ss)
{
    float vv[8] = {a.x, a.y, a.z, a.w, b.x, b.y, b.z, b.w};
    v8u uh, ul;
#pragma unroll
    for (int j = 0; j < 8; ++j) {
        float v = vv[j];
        unsigned short hh = f16b(v);
        uh[j] = hh;
        ul[j] = f16b(v - f16f(hh));   // exact residual in f32, then RNE
        ss    = fmaf(v, v, ss);
    }
    ah = __builtin_bit_cast(v8h, uh);
    al = __builtin_bit_cast(v8h, ul);
}

// 64 tokens/block, 512 thr (8 waves), grid = 256 = exactly 1 block/CU.
// Wave w owns k-range [w*256, w*256+256) for ALL 64 tokens (four 16-row
// M tiles). IDENTICAL to R4 except __launch_bounds__(512, 1):
// the 2nd launch-bounds arg acts as min-BLOCKS-per-CU (CUDA semantics,
// established from R0-R4 VGPR counts), so R4's (512,2) capped VGPRs at 128
// against ~190 live -> 49.7 MB of scratch spill traffic (WRITE_SIZE).
// (512,1) -> 256-VGPR cap -> no spill; LDS (134.5 KB) + grid already limit
// residency to 1 block/CU, so nothing is lost.
// logits_raw = Xh*Wh + Xh*Wl + Xl*Wh  (split-f16, per-acc order == R3/R4).
__global__ __launch_bounds__(512, 1) void router_main(
    const float* __restrict__ h, const unsigned short* __restrict__ wf,
    const float* __restrict__ pes,
    float* __restrict__ out_w, float* __restrict__ out_i, float* __restrict__ out_c)
{
    __shared__ __align__(16) float lg[8 * 64 * 66];   // [wave][token][expert+pad] 135168B
    __shared__ float lss[8 * 64];                     // [wave][token] partial sumsq
    __shared__ int   hist[NEXPERT];

    const int tid  = (int)threadIdx.x;
    const int w    = __builtin_amdgcn_readfirstlane(tid >> 6);   // wave 0..7
    const int lane = tid & 63;
    const int m    = lane & 15;                                   // A row idx
    const int quad = lane >> 4;
    const int t0   = (int)blockIdx.x * TOKB;

    if (tid < NEXPERT) hist[tid] = 0;

    // A sources: token rows t*16+m, k = w*256 + s*32 + quad*8 + j
    const float* xp0 = h + (size_t)(t0 + m) * HIDDEN + w * 256 + quad * 8;
    const float* xp1 = xp0 + (size_t)16 * HIDDEN;
    const float* xp2 = xp0 + (size_t)32 * HIDDEN;
    const float* xp3 = xp0 + (size_t)48 * HIDDEN;
    // B source: ks = w*8 + s; frag base = ks*4096 + nt*1024 (+512 for lo)
    const unsigned short* wq = wf + (size_t)(w * 8) * 4096 + (size_t)lane * 8;

    v4f acc[4][4];                                    // [tile][nt]
#pragma unroll
    for (int t = 0; t < 4; ++t)
#pragma unroll
        for (int nt = 0; nt < 4; ++nt) acc[t][nt] = (v4f)0.f;
    float ss[4] = {0.f, 0.f, 0.f, 0.f};

    float4 ca[4], cb[4];
    ca[0] = *(const float4*)xp0; cb[0] = *(const float4*)(xp0 + 4);
    ca[1] = *(const float4*)xp1; cb[1] = *(const float4*)(xp1 + 4);
    ca[2] = *(const float4*)xp2; cb[2] = *(const float4*)(xp2 + 4);
    ca[3] = *(const float4*)xp3; cb[3] = *(const float4*)(xp3 + 4);

#pragma unroll
    for (int s = 0; s < 8; ++s) {
        // ---- issue ALL memory for this step first (8 B-frags + next X), then fence
        const unsigned short* bq = wq + (size_t)s * 4096;
        v8h bh[4], bl[4];
#pragma unroll
        for (int nt = 0; nt < 4; ++nt) {
            bh[nt] = *(const v8h*)(bq + nt * 1024);
            bl[nt] = *(const v8h*)(bq + nt * 1024 + 512);
        }
        float4 na[4], nb[4];
        if (s < 7) {
            na[0] = *(const float4*)(xp0 + (s + 1) * 32);
            nb[0] = *(const float4*)(xp0 + (s + 1) * 32 + 4);
            na[1] = *(const float4*)(xp1 + (s + 1) * 32);
            nb[1] = *(const float4*)(xp1 + (s + 1) * 32 + 4);
            na[2] = *(const float4*)(xp2 + (s + 1) * 32);
            nb[2] = *(const float4*)(xp2 + (s + 1) * 32 + 4);
            na[3] = *(const float4*)(xp3 + (s + 1) * 32);
            nb[3] = *(const float4*)(xp3 + (s + 1) * 32 + 4);
        }
        __builtin_amdgcn_sched_barrier(0);   // loads above, consumers below

        // ---- per tile: convert current X (overlaps load latency), 12 MFMAs.
        // Per-acc order (ah*bh, ah*bl, al*bh) identical to R3/R4.
#pragma unroll
        for (int t = 0; t < 4; ++t) {
            v8h ah, al;
            cvt8(ca[t], cb[t], ah, al, ss[t]);
#pragma unroll
            for (int nt = 0; nt < 4; ++nt) {
                acc[t][nt] = __builtin_amdgcn_mfma_f32_16x16x32_f16(ah, bh[nt], acc[t][nt], 0, 0, 0);
                acc[t][nt] = __builtin_amdgcn_mfma_f32_16x16x32_f16(ah, bl[nt], acc[t][nt], 0, 0, 0);
                acc[t][nt] = __builtin_amdgcn_mfma_f32_16x16x32_f16(al, bh[nt], acc[t][nt], 0, 0, 0);
            }
        }

        if (s < 7) {
#pragma unroll
            for (int t = 0; t < 4; ++t) { ca[t] = na[t]; cb[t] = nb[t]; }
        }
    }

    // ---- sum of squares: lane holds quad's 64-float share of rows t*16+m
#pragma unroll
    for (int t = 0; t < 4; ++t) {
        float s = ss[t];
        s += __shfl_xor(s, 16, 64);
        s += __shfl_xor(s, 32, 64);
        if (lane < 16) lss[w * 64 + t * 16 + lane] = s;
    }

    // ---- raw logit partials: D row=(quad*4+reg)=token-in-tile, col=nt*16+m
#pragma unroll
    for (int t = 0; t < 4; ++t)
#pragma unroll
        for (int nt = 0; nt < 4; ++nt)
#pragma unroll
            for (int r = 0; r < 4; ++r)
                lg[(w * 64 + t * 16 + quad * 4 + r) * 66 + nt * 16 + m] = acc[t][nt][r];
    __syncthreads();

    // ---- top-8 epilogue (R0-verified): wave w handles tokens w*8..w*8+7
    for (int i = 0; i < 8; ++i) {
        const int tok = w * 8 + i;
        float l0 = lg[(0 * 64 + tok) * 66 + lane], l1 = lg[(1 * 64 + tok) * 66 + lane];
        float l2 = lg[(2 * 64 + tok) * 66 + lane], l3 = lg[(3 * 64 + tok) * 66 + lane];
        float l4 = lg[(4 * 64 + tok) * 66 + lane], l5 = lg[(5 * 64 + tok) * 66 + lane];
        float l6 = lg[(6 * 64 + tok) * 66 + lane], l7 = lg[(7 * 64 + tok) * 66 + lane];
        float lsum = ((l0 + l1) + (l2 + l3)) + ((l4 + l5) + (l6 + l7));
        float q01 = lss[0 * 64 + tok] + lss[1 * 64 + tok];
        float q23 = lss[2 * 64 + tok] + lss[3 * 64 + tok];
        float q45 = lss[4 * 64 + tok] + lss[5 * 64 + tok];
        float q67 = lss[6 * 64 + tok] + lss[7 * 64 + tok];
        double sst = (double)((q01 + q23) + (q45 + q67));
        double rr  = 1.0 / sqrt(sst * (1.0 / (double)HIDDEN) + 1e-6);
        float logit = (float)((double)lsum * rr * (RSQRT_H / (double)WSCALE));

        float work = logit;
        float myval = 0.f; int myidx = 0; float m0 = 0.f;
#pragma unroll
        for (int j = 0; j < TOPK; ++j) {
            float mx = work;
#pragma unroll
            for (int off = 32; off; off >>= 1) mx = fmaxf(mx, __shfl_xor(mx, off, 64));
            unsigned long long msk = __ballot(work == mx);
            int src = __ffsll((long long)msk) - 1;   // ties -> lowest index (jax)
            if (j == 0) m0 = mx;
            if (lane == j) { myval = mx; myidx = src; }
            if (lane == src) work = -3.402823466e38f;
        }

        float ev = (lane < TOPK) ? expf(myval - m0) : 0.f;
        float es = ev;
        es += __shfl_xor(es, 1, 64);
        es += __shfl_xor(es, 2, 64);
        es += __shfl_xor(es, 4, 64);
        if (lane < TOPK) {
            float wgt = (ev / es) * pes[myidx];
            size_t o = (size_t)(t0 + tok) * TOPK + lane;
            out_w[o] = wgt;
            out_i[o] = (float)myidx;                 // d_out read as float32
            atomicAdd(&hist[myidx], 1);
        }
    }

    __syncthreads();
    if (tid < NEXPERT)
        atomicAdd(&out_c[tid], (float)hist[tid]);    // counts are exact small ints
}

extern "C" void kernel_launch(void* const* d_in, const int* in_sizes, int n_in,
                              void* d_out, int out_size, void* d_ws, size_t ws_size,
                              hipStream_t stream) {
    const float* h     = (const float*)d_in[0];   // [4,4096,2048] f32
    const float* scale = (const float*)d_in[1];   // [2048] f32
    const float* w     = (const float*)d_in[2];   // [64,2048] f32
    const float* pes   = (const float*)d_in[3];   // [64] f32

    unsigned short* wf = (unsigned short*)d_ws;   // 512 KB f16 fragment bank

    float* out_w = (float*)d_out;                                  // [16384,8]
    float* out_i = (float*)d_out + (size_t)NTOK * TOPK;            // [16384,8] idx-as-f32
    float* out_c = (float*)d_out + (size_t)NTOK * TOPK * 2;        // [64]

    prep_wf<<<512, 256, 0, stream>>>(w, scale, wf, out_c);

    // 256 blocks x 512 thr (8 waves); exactly 1 block/CU
    router_main<<<NTOK / TOKB, 512, 0, stream>>>(h, wf, pes, out_w, out_i, out_c);
}